// Round 1
// 398.252 us; speedup vs baseline: 1.3169x; 1.3169x over previous
//
#include <hip/hip_runtime.h>

// Fused MLP: o = silu(x @ w1) @ w2 per head. H=16, N=8192, D=256, I=1024, fp32.
// bf16 MFMA 32x32x16. Block = 512 thr (8 waves), tile = 128 rows x D=256.
//
// v2: weights are pre-converted to bf16 ONCE per launch by prep_weights into
// d_ws (needs ws_size >= 16 MiB), laid out as the exact XOR-swizzled byte
// image the main kernel's LDS wants:
//   w1 chunk image (per h,c): ushort[64 i][32 slot][8], slot = (d>>3) ^ (i&31)
//   w2 chunk image (per h,c): ushort[256 d][8 slot][8], slot = (i>>3) ^ (d&7)
// Main kernel stages them with global_load_lds (zero VALU, zero staging regs),
// double-buffered, raw s_barrier + counted s_waitcnt vmcnt(N) (never drains
// to 0 mid-loop). GEMM1 A-reads are bank-conflict-free (32 distinct 16B slots
// per 32 lanes); GEMM2/h reads are 2-way (free). Silu uses v_rcp_f32.
// XCD-aware bijective block swizzle (1024 blocks, %8==0).

#define Hn 16
#define Nn 8192
#define Dn 256
#define In 1024
#define TN 128
#define IC 64
#define NCH (In / IC)  // 16
#define BS 512
#define CHW1 (IC * Dn)  // 16384 ushorts = 32768 B per w1 chunk image
#define CHW2 (Dn * IC)  // 16384 ushorts = 32768 B per w2 chunk image

typedef __bf16 bf16x8 __attribute__((ext_vector_type(8)));
typedef unsigned short ushortx4 __attribute__((ext_vector_type(4)));
typedef unsigned short ushortx8 __attribute__((ext_vector_type(8)));
typedef float floatx4 __attribute__((ext_vector_type(4)));
typedef float floatx16 __attribute__((ext_vector_type(16)));

__device__ __forceinline__ unsigned short bfbits(float f) {
  __bf16 b = (__bf16)f;  // RNE, compiler pairs into v_cvt_pk_bf16_f32
  return __builtin_bit_cast(unsigned short, b);
}

// ---------------------------------------------------------------------------
// prep: fp32 weights -> bf16 swizzled chunk images in workspace
// blocks 0..255: w1 (h = b>>4, c = b&15); blocks 256..511: w2.
// ---------------------------------------------------------------------------
__global__ __launch_bounds__(256) void prep_weights(
    const float* __restrict__ w1, const float* __restrict__ w2,
    unsigned short* __restrict__ ws1, unsigned short* __restrict__ ws2) {
  __shared__ __align__(16) unsigned short tile[256 * 80];  // 40960 B
  const int b = blockIdx.x;
  const int t = threadIdx.x;
  if (b < Hn * NCH) {
    const int hd = b >> 4, c = b & 15;
    const float* src = w1 + (size_t)hd * Dn * In + c * IC;  // w1[hd][d][c*64+..]
    const int lane = t & 63, rg = t >> 6;
    // coalesced read w1[hd][d][c*64 + lane], tile[i=lane][d], stride 272
#pragma unroll 4
    for (int r = 0; r < 64; ++r) {
      const int d = r * 4 + rg;
      tile[lane * 272 + d] = bfbits(src[(size_t)d * In + lane]);
    }
    __syncthreads();
    unsigned short* dst = ws1 + (size_t)b * CHW1;
#pragma unroll
    for (int k = 0; k < 8; ++k) {
      const int slot = k * 256 + t;  // 2048 slots of 16B
      const int i = slot >> 5, ps = slot & 31, ls = ps ^ (i & 31);
      *(ushortx8*)&dst[slot * 8] = *(const ushortx8*)&tile[i * 272 + ls * 8];
    }
  } else {
    const int bb = b - Hn * NCH;
    const int hd = bb >> 4, c = bb & 15;
    const float* src = w2 + (size_t)hd * In * Dn + (size_t)(c * IC) * Dn;
    // coalesced read w2[hd][c*64+il][t], tile[d=t][il], stride 80
#pragma unroll 4
    for (int il = 0; il < 64; ++il) {
      tile[t * 80 + il] = bfbits(src[(size_t)il * Dn + t]);
    }
    __syncthreads();
    unsigned short* dst = ws2 + (size_t)bb * CHW2;
#pragma unroll
    for (int k = 0; k < 8; ++k) {
      const int slot = k * 256 + t;
      const int d = slot >> 3, ps = slot & 7, ls = ps ^ (d & 7);
      *(ushortx8*)&dst[slot * 8] = *(const ushortx8*)&tile[d * 80 + ls * 8];
    }
  }
}

// ---------------------------------------------------------------------------
// main fused kernel
// ---------------------------------------------------------------------------
#define ISSUE(gbase, lbase)                                                    \
  {                                                                            \
    const char* g_ = (const char*)(gbase) + (wid << 12) + (l << 4);            \
    char* s_ = (char*)(lbase) + (wid << 12);                                   \
    _Pragma("unroll") for (int t_ = 0; t_ < 4; ++t_)                           \
        __builtin_amdgcn_global_load_lds(                                      \
            (const __attribute__((address_space(1))) unsigned int*)(g_ +       \
                                                                 (t_ << 10)),  \
            (__attribute__((address_space(3))) unsigned int*)(s_ + (t_ << 10)),\
            16, 0, 0);                                                         \
  }

__global__ __launch_bounds__(BS, 2) void fused_mlp(
    const float* __restrict__ x, float* __restrict__ out,
    const unsigned short* __restrict__ ws1,
    const unsigned short* __restrict__ ws2) {
  __shared__ __align__(16) unsigned short lw1[2][CHW1];  // 2 x 32768 B
  __shared__ __align__(16) unsigned short lw2[2][CHW2];  // 2 x 32768 B
  __shared__ __align__(16) unsigned short lh[TN * IC];   // 16384 B  (=144 KiB)

  const int tid = threadIdx.x;
  const int wid = tid >> 6;
  const int l = tid & 63;
  const int half = l >> 5;
  const int l31 = l & 31;
  const int ti = wid & 1;   // GEMM1: i-tile
  const int tn = wid >> 1;  // GEMM1: n-tile
  const int td = wid & 3;   // GEMM2: d macro-tile
  const int tn2 = wid >> 2; // GEMM2: n macro-tile
  const int x7 = l31 & 7;

  // bijective XCD swizzle: 1024 wgs, each XCD gets 128 consecutive work ids
  const int bid = blockIdx.x;
  const int wk = (bid & 7) * 128 + (bid >> 3);
  const int hd = wk >> 6;
  const int n0 = (wk & 63) * TN;

  const float* xg = x + (size_t)hd * Nn * Dn + (size_t)n0 * Dn;
  float* og = out + (size_t)hd * Nn * Dn + (size_t)n0 * Dn;
  const unsigned short* w1i = ws1 + (size_t)(hd * NCH) * CHW1;
  const unsigned short* w2i = ws2 + (size_t)(hd * NCH) * CHW2;

  // --- x -> registers as GEMM1 B-frags: lane holds x[n=32*tn+l31][16s+8half+j]
  bf16x8 xa[16];
  {
    const float* xr = xg + (size_t)(32 * tn + l31) * Dn + half * 8;
#pragma unroll
    for (int s = 0; s < 16; ++s) {
      floatx4 v0 = *(const floatx4*)(xr + 16 * s);
      floatx4 v1 = *(const floatx4*)(xr + 16 * s + 4);
      bf16x8 t;
#pragma unroll
      for (int j = 0; j < 4; ++j) {
        t[j] = (__bf16)v0[j];
        t[4 + j] = (__bf16)v1[j];
      }
      xa[s] = t;
    }
  }

  // precomputed swizzled byte offsets (loop-invariant)
  int o1[16];
#pragma unroll
  for (int s = 0; s < 16; ++s) o1[s] = ((2 * s + half) ^ l31) << 4;
  int o2[4], oh[4];
#pragma unroll
  for (int s = 0; s < 4; ++s) o2[s] = ((2 * s + half) ^ x7) << 4;
#pragma unroll
  for (int rg = 0; rg < 4; ++rg) oh[rg] = ((4 * ti + rg) ^ x7) << 4;

  floatx16 oacc[2][2];
#pragma unroll
  for (int a = 0; a < 2; ++a)
#pragma unroll
    for (int b = 0; b < 2; ++b)
#pragma unroll
      for (int e = 0; e < 16; ++e) oacc[a][b][e] = 0.f;

  // prologue: clean vmcnt, then stage chunk 0
  asm volatile("s_waitcnt vmcnt(0)" ::: "memory");
  ISSUE(w1i, lw1[0]);
  ISSUE(w2i, lw2[0]);
  asm volatile("s_waitcnt vmcnt(4)" ::: "memory");  // w1(0) landed, w2(0) flying
  __builtin_amdgcn_s_barrier();

  for (int c = 0; c < NCH; ++c) {
    const int pb = c & 1;
    // prefetch next chunk into the other buffer (freed at last B_end)
    if (c + 1 < NCH) {
      ISSUE(w1i + (size_t)(c + 1) * CHW1, lw1[pb ^ 1]);
      ISSUE(w2i + (size_t)(c + 1) * CHW2, lw2[pb ^ 1]);
    }

    // --- GEMM1: z^T[32ti..][32tn..] = w1^T x^T, K=256, 2 acc chains ---
    floatx16 z0, z1;
#pragma unroll
    for (int e = 0; e < 16; ++e) {
      z0[e] = 0.f;
      z1[e] = 0.f;
    }
    const char* a1p = (const char*)lw1[pb] + (32 * ti + l31) * 512;
#pragma unroll
    for (int s = 0; s < 8; ++s) {
      bf16x8 A0 = *(const bf16x8*)(a1p + o1[2 * s]);
      z0 = __builtin_amdgcn_mfma_f32_32x32x16_bf16(A0, xa[2 * s], z0, 0, 0, 0);
      bf16x8 A1 = *(const bf16x8*)(a1p + o1[2 * s + 1]);
      z1 = __builtin_amdgcn_mfma_f32_32x32x16_bf16(A1, xa[2 * s + 1], z1, 0, 0, 0);
    }

    // --- silu -> h[n][i] (swizzled b64 writes) ---
    char* hw = (char*)lh + (32 * tn + l31) * 128 + 8 * half;
#pragma unroll
    for (int rg = 0; rg < 4; ++rg) {
      ushortx4 t;
#pragma unroll
      for (int r = 0; r < 4; ++r) {
        float z = z0[4 * rg + r] + z1[4 * rg + r];
        t[r] = bfbits(z * __builtin_amdgcn_rcpf(1.f + __expf(-z)));
      }
      *(ushortx4*)(hw + oh[rg]) = t;
    }

    // B_mid: h visible + everyone's w2(c) landed. Counted wait: outstanding
    // = w2(c)[4] + w1(c+1)[4] + w2(c+1)[4] -> vmcnt(8) retires w2(c).
    if (c + 1 < NCH)
      asm volatile("s_waitcnt vmcnt(8)" ::: "memory");
    else
      asm volatile("s_waitcnt vmcnt(0)" ::: "memory");
    asm volatile("s_waitcnt lgkmcnt(0)" ::: "memory");
    __builtin_amdgcn_s_barrier();

    // --- GEMM2: o^T += w2^T h^T, K=64 ---
    const char* a2p = (const char*)lw2[pb] + (64 * td + l31) * 128;
    const char* b2p = (const char*)lh + (64 * tn2 + l31) * 128;
#pragma unroll
    for (int s = 0; s < 4; ++s) {
      bf16x8 A0 = *(const bf16x8*)(a2p + o2[s]);
      bf16x8 A1 = *(const bf16x8*)(a2p + 4096 + o2[s]);
      bf16x8 B0 = *(const bf16x8*)(b2p + o2[s]);
      bf16x8 B1 = *(const bf16x8*)(b2p + 4096 + o2[s]);
      oacc[0][0] = __builtin_amdgcn_mfma_f32_32x32x16_bf16(A0, B0, oacc[0][0], 0, 0, 0);
      oacc[0][1] = __builtin_amdgcn_mfma_f32_32x32x16_bf16(A0, B1, oacc[0][1], 0, 0, 0);
      oacc[1][0] = __builtin_amdgcn_mfma_f32_32x32x16_bf16(A1, B0, oacc[1][0], 0, 0, 0);
      oacc[1][1] = __builtin_amdgcn_mfma_f32_32x32x16_bf16(A1, B1, oacc[1][1], 0, 0, 0);
    }

    // B_end: my reads of lw*[pb]/lh done + everyone's w1(c+1) landed.
    // Outstanding = w1(c+1)[4] + w2(c+1)[4] -> vmcnt(4) retires w1(c+1).
    if (c + 1 < NCH) {
      asm volatile("s_waitcnt vmcnt(4) lgkmcnt(0)" ::: "memory");
      __builtin_amdgcn_s_barrier();
    }
  }

  // --- epilogue: o^T C-layout -> out[n][d] as float4 ---
#pragma unroll
  for (int cd = 0; cd < 2; ++cd) {
#pragma unroll
    for (int cn = 0; cn < 2; ++cn) {
      const int n = 64 * tn2 + 32 * cn + l31;
#pragma unroll
      for (int rg = 0; rg < 4; ++rg) {
        floatx4 v;
#pragma unroll
        for (int r = 0; r < 4; ++r) v[r] = oacc[cd][cn][4 * rg + r];
        const int d0 = 64 * td + 32 * cd + 8 * rg + 4 * half;
        *(floatx4*)(og + (size_t)n * Dn + d0) = v;
      }
    }
  }
}

extern "C" void kernel_launch(void* const* d_in, const int* in_sizes, int n_in,
                              void* d_out, int out_size, void* d_ws,
                              size_t ws_size, hipStream_t stream) {
  const float* x = (const float*)d_in[0];
  const float* w1 = (const float*)d_in[1];
  const float* w2 = (const float*)d_in[2];
  float* out = (float*)d_out;
  unsigned short* ws1 = (unsigned short*)d_ws;                 // 8 MiB
  unsigned short* ws2 = ws1 + (size_t)Hn * NCH * CHW1;         // +8 MiB
  (void)in_sizes; (void)n_in; (void)out_size; (void)ws_size;   // needs >=16 MiB
  hipLaunchKernelGGL(prep_weights, dim3(2 * Hn * NCH), dim3(256), 0, stream,
                     w1, w2, ws1, ws2);
  hipLaunchKernelGGL(fused_mlp, dim3(Hn * (Nn / TN)), dim3(BS), 0, stream,
                     x, out, ws1, ws2);
}